// Round 5
// baseline (239.917 us; speedup 1.0000x reference)
//
#include <hip/hip_runtime.h>
#include <hip/hip_cooperative_groups.h>
#include <math.h>

namespace cg = cooperative_groups;

#define N_AG 8192
#define SD 64
#define HD 128
#define CD 32
#define AD 8
#define NBLK 512
#define APB 16   // agents per block

// ws layout (floats): per-block msum partials, then global hsum accumulator
#define MPARTS_OFF 0                 // NBLK*CD
#define HSUM_OFF   (NBLK * CD)       // HD

__global__ __launch_bounds__(256, 2)
void fused_mas(const float* __restrict__ X, const float* __restrict__ noise,
               const float* __restrict__ W1, const float* __restrict__ b1,
               const float* __restrict__ W2, const float* __restrict__ b2,
               const float* __restrict__ Wc, const float* __restrict__ bc,
               const float* __restrict__ Wg, const float* __restrict__ bg,
               const float* __restrict__ Wp, const float* __restrict__ bp,
               const float* __restrict__ Wv, const float* __restrict__ bv,
               const float* __restrict__ Wr, const float* __restrict__ br,
               float* __restrict__ ws, float* __restrict__ out)
{
    cg::grid_group grid = cg::this_grid();
    __shared__ float sX[APB][SD];        // 4 KB
    __shared__ float sP[APB][HD];        // 8 KB   raw P = X@W1a + b1
    __shared__ float sT[APB][HD];        // 8 KB   relu(P)
    __shared__ float sU[APB][HD];        // 8 KB   u = relu(P)@W2 + b2
    __shared__ float sM[APB][CD + 1];    // msgs pre-norm (+1 pad: rinv reads row-wise)
    __shared__ float sR[APB];
    __shared__ float sMsum[CD];
    __shared__ float sVec[HD];           // cvec, then u2
    __shared__ float sVec2[HD];          // hmean, then g
    __shared__ float sRed[256];

    const int tid = threadIdx.x;
    const int b = blockIdx.x;
    const int a0 = b * APB;

    // ================= phase 1: X -> P,T,U,M, per-agent l2norm, block msum partial
    for (int i = tid; i < APB * SD; i += 256)
        sX[i >> 6][i & 63] = X[a0 * SD + i];
    if (b == 0 && tid < HD) ws[HSUM_OFF + tid] = 0.f;   // zero hsum before grid.sync #1
    __syncthreads();

    {   // P: thread owns column c for 8 agents; weight loaded once per k
        const int c = tid & 127;
        const int ag0 = tid >> 7;        // 0 or 1
        float acc[8];
        #pragma unroll
        for (int i = 0; i < 8; ++i) acc[i] = b1[c];
        for (int k = 0; k < SD; ++k) {
            float w = W1[k * HD + c];
            #pragma unroll
            for (int i = 0; i < 8; ++i) acc[i] += sX[ag0 + 2 * i][k] * w;
        }
        #pragma unroll
        for (int i = 0; i < 8; ++i) {
            int ag = ag0 + 2 * i;
            sP[ag][c] = acc[i];
            sT[ag][c] = fmaxf(acc[i], 0.f);
        }
    }
    __syncthreads();
    {   // U = relu(P) @ W2 + b2
        const int c = tid & 127;
        const int ag0 = tid >> 7;
        float acc[8];
        #pragma unroll
        for (int i = 0; i < 8; ++i) acc[i] = b2[c];
        for (int k = 0; k < HD; ++k) {
            float w = W2[k * HD + c];
            #pragma unroll
            for (int i = 0; i < 8; ++i) acc[i] += sT[ag0 + 2 * i][k] * w;
        }
        #pragma unroll
        for (int i = 0; i < 8; ++i) sU[ag0 + 2 * i][c] = acc[i];
    }
    __syncthreads();
    {   // M = U @ Wc + bc
        const int c = tid & 31;
        const int ag0 = tid >> 5;        // 0..7; handles ag0 and ag0+8
        float acc0 = bc[c], acc1 = bc[c];
        for (int k = 0; k < HD; ++k) {
            float w = Wc[k * CD + c];
            acc0 += sU[ag0][k] * w;
            acc1 += sU[ag0 + 8][k] * w;
        }
        sM[ag0][c] = acc0;
        sM[ag0 + 8][c] = acc1;
    }
    __syncthreads();
    if (tid < APB) {
        float ss = 0.f;
        #pragma unroll
        for (int c2 = 0; c2 < CD; ++c2) { float m = sM[tid][c2]; ss += m * m; }
        sR[tid] = 1.f / fmaxf(sqrtf(ss), 1e-12f);
    }
    __syncthreads();
    if (tid < CD) {
        float s = 0.f;
        #pragma unroll
        for (int ag = 0; ag < APB; ++ag) s += sM[ag][tid] * sR[ag];
        ws[MPARTS_OFF + b * CD + tid] = s;
    }
    grid.sync();

    // ================= phase 2: reduce msum parts, cvec, h2 colsum -> atomic hsum
    {
        const int c = tid & 31, chunk = tid >> 5;   // 8 chunks x 64 parts = 512
        float s = 0.f;
        for (int p = chunk * 64; p < chunk * 64 + 64; ++p)
            s += ws[MPARTS_OFF + p * CD + c];
        sRed[tid] = s;
    }
    __syncthreads();
    if (tid < CD) {
        float s = 0.f;
        #pragma unroll
        for (int j = 0; j < 8; ++j) s += sRed[j * 32 + tid];
        sMsum[tid] = s;
    }
    __syncthreads();
    if (tid < HD) {   // cvec = (msum/N) @ W1b
        float s = 0.f;
        #pragma unroll
        for (int k = 0; k < CD; ++k) s += sMsum[k] * W1[(SD + k) * HD + tid];
        sVec[tid] = s * (1.f / (float)N_AG);
    }
    __syncthreads();
    {   // colsum of relu(P + cvec) over this block's agents
        const int c = tid & 127, half = tid >> 7;
        float part = 0.f;
        #pragma unroll
        for (int ag = half; ag < APB; ag += 2)
            part += fmaxf(sP[ag][c] + sVec[c], 0.f);
        sRed[tid] = part;
    }
    __syncthreads();
    if (tid < HD) atomicAdd(&ws[HSUM_OFF + tid], sRed[tid] + sRed[tid + 128]);
    grid.sync();

    // ================= phase 3: g = relu(((hsum/N)@W2 + b2)@Wg + bg), redundant/block
    if (tid < HD) sVec2[tid] = ws[HSUM_OFF + tid] * (1.f / (float)N_AG);
    __syncthreads();
    if (tid < HD) {
        float s = b2[tid];
        for (int k = 0; k < HD; ++k) s += sVec2[k] * W2[k * HD + tid];
        sVec[tid] = s;
    }
    __syncthreads();
    if (tid < HD) {
        float s = bg[tid];
        for (int k = 0; k < HD; ++k) s += sVec[k] * Wg[k * HD + tid];
        sVec2[tid] = fmaxf(s, 0.f);     // g
    }
    __syncthreads();

    // ================= phase 4: per-agent normalize + heads (wave per agent)
    const int lane = tid & 63;
    const int w = tid >> 6;
    float wp0[AD], wp1[AD];
    #pragma unroll
    for (int j = 0; j < AD; ++j) { wp0[j] = Wp[lane * AD + j]; wp1[j] = Wp[(lane + 64) * AD + j]; }
    float wv0 = Wv[lane], wv1 = Wv[lane + 64];
    float wr0[3], wr1[3];
    #pragma unroll
    for (int j = 0; j < 3; ++j) { wr0[j] = Wr[lane * 3 + j]; wr1[j] = Wr[(lane + 64) * 3 + j]; }
    const float g0 = sVec2[lane], g1 = sVec2[lane + 64];
    const float bpl = (lane < AD) ? bp[lane] : 0.f;
    const float bv0 = bv[0];
    const float br0 = br[0], br1 = br[1], br2 = br[2];

    float* outH = out;
    float* outA = out + N_AG * HD;
    float* outV = outA + N_AG * AD;
    float* outR = outV + N_AG;

    for (int ag = w; ag < APB; ag += 4) {
        int a = a0 + ag;
        float v0 = g0 + 0.01f * noise[a * HD + lane];
        float v1 = g1 + 0.01f * noise[a * HD + 64 + lane];
        float ss = v0 * v0 + v1 * v1;
        #pragma unroll
        for (int off = 32; off; off >>= 1) ss += __shfl_xor(ss, off);
        float rinv = 1.f / fmaxf(sqrtf(ss), 1e-12f);
        float h0 = v0 * rinv, h1 = v1 * rinv;
        outH[a * HD + lane]      = h0;
        outH[a * HD + 64 + lane] = h1;
        float acc[12];
        #pragma unroll
        for (int j = 0; j < AD; ++j) acc[j] = h0 * wp0[j] + h1 * wp1[j];
        acc[8] = h0 * wv0 + h1 * wv1;
        #pragma unroll
        for (int j = 0; j < 3; ++j) acc[9 + j] = h0 * wr0[j] + h1 * wr1[j];
        #pragma unroll
        for (int j = 0; j < 12; ++j) {
            #pragma unroll
            for (int off = 32; off; off >>= 1) acc[j] += __shfl_xor(acc[j], off);
        }
        if (lane < AD) {
            outA[a * AD + lane] = tanhf(acc[lane] + bpl);
        } else if (lane == 8) {
            outV[a] = acc[8] + bv0;
        } else if (lane >= 9 && lane < 12) {
            float l0 = acc[9] + br0, l1 = acc[10] + br1, l2 = acc[11] + br2;
            float m = fmaxf(l0, fmaxf(l1, l2));
            float e0 = expf(l0 - m), e1 = expf(l1 - m), e2 = expf(l2 - m);
            float denom = e0 + e1 + e2;
            float mine = (lane == 9) ? e0 : (lane == 10) ? e1 : e2;
            outR[a * 3 + (lane - 9)] = mine / denom;
        }
    }
}

extern "C" void kernel_launch(void* const* d_in, const int* in_sizes, int n_in,
                              void* d_out, int out_size, void* d_ws, size_t ws_size,
                              hipStream_t stream) {
    const float* states = (const float*)d_in[0];
    const float* noise  = (const float*)d_in[1];
    const float* W1 = (const float*)d_in[2];
    const float* b1 = (const float*)d_in[3];
    const float* W2 = (const float*)d_in[4];
    const float* b2 = (const float*)d_in[5];
    const float* Wc = (const float*)d_in[6];
    const float* bc = (const float*)d_in[7];
    const float* Wg = (const float*)d_in[8];
    const float* bg = (const float*)d_in[9];
    const float* Wp = (const float*)d_in[10];
    const float* bp = (const float*)d_in[11];
    const float* Wv = (const float*)d_in[12];
    const float* bv = (const float*)d_in[13];
    const float* Wr = (const float*)d_in[14];
    const float* br = (const float*)d_in[15];
    float* ws  = (float*)d_ws;
    float* out = (float*)d_out;

    void* args[] = {
        (void*)&states, (void*)&noise,
        (void*)&W1, (void*)&b1, (void*)&W2, (void*)&b2,
        (void*)&Wc, (void*)&bc, (void*)&Wg, (void*)&bg,
        (void*)&Wp, (void*)&bp, (void*)&Wv, (void*)&bv,
        (void*)&Wr, (void*)&br, (void*)&ws, (void*)&out
    };
    hipLaunchCooperativeKernel((void*)fused_mas, dim3(NBLK), dim3(256), args, 0, stream);
}

// Round 6
// 149.037 us; speedup vs baseline: 1.6098x; 1.6098x over previous
//
#include <hip/hip_runtime.h>
#include <math.h>

#define N_AG 8192
#define SD 64
#define HD 128
#define CD 32
#define AD 8

// ws layout (floats)
#define P_OFF     0                        // N_AG*HD = 1048576
#define W2CT_OFF  (N_AG*HD)                // 32*128 (W2c transposed: [c][k])
#define WALLT_OFF (W2CT_OFF + CD*HD)       // 12*128 (head weights transposed: [j][k])
#define BALL_OFF  (WALLT_OFF + 12*HD)      // 16 (12 used)
#define BCP_OFF   (BALL_OFF + 16)          // 32
#define MSUM_OFF  (BCP_OFF + CD)           // 32
#define HSUM_OFF  (MSUM_OFF + CD)          // 128

// ---------------- K0: W2cT = (W2@Wc)^T, bc' = b2@Wc+bc, WallT/ball, zero accums
__global__ void k0_pre(const float* __restrict__ W2, const float* __restrict__ b2,
                       const float* __restrict__ Wc, const float* __restrict__ bc,
                       const float* __restrict__ Wp, const float* __restrict__ bp,
                       const float* __restrict__ Wv, const float* __restrict__ bv,
                       const float* __restrict__ Wr, const float* __restrict__ br,
                       float* __restrict__ ws) {
    int t = threadIdx.x, b = blockIdx.x;
    if (b < 16) {
        int idx = b * 256 + t;             // [0,4096)
        int c = idx & 31, k = idx >> 5;    // k in [0,128)
        float s = 0.f;
        #pragma unroll 16
        for (int j = 0; j < HD; ++j) s += W2[k*HD + j] * Wc[j*CD + c];
        ws[W2CT_OFF + c*HD + k] = s;       // transposed store
    } else if (b == 16) {
        if (t < CD) {
            float s = bc[t];
            for (int j = 0; j < HD; ++j) s += b2[j] * Wc[j*CD + t];
            ws[BCP_OFF + t] = s;
            ws[MSUM_OFF + t] = 0.f;
        } else if (t >= 64 && t < 192) {
            ws[HSUM_OFF + t - 64] = 0.f;
        }
    } else {
        for (int idx = t; idx < 12 * HD; idx += 256) {
            int j = idx >> 7, k = idx & 127;
            float v = (j < 8) ? Wp[k*AD + j] : (j == 8) ? Wv[k] : Wr[k*3 + (j - 9)];
            ws[WALLT_OFF + idx] = v;       // WallT[j][k]
        }
        if (t < 12) ws[BALL_OFF + t] = (t < 8) ? bp[t] : (t == 8) ? bv[0] : br[t - 9];
    }
}

#define FMA4(acc, xv, w0, w1, w2, w3)                                   \
    acc.x += xv.x*w0.x + xv.y*w1.x + xv.z*w2.x + xv.w*w3.x;             \
    acc.y += xv.x*w0.y + xv.y*w1.y + xv.z*w2.y + xv.w*w3.y;             \
    acc.z += xv.x*w0.z + xv.y*w1.z + xv.z*w2.z + xv.w*w3.z;             \
    acc.w += xv.x*w0.w + xv.y*w1.w + xv.z*w2.w + xv.w*w3.w;

// ---------------- K1: P = X@W1a + b1 (store f4), msgs = l2norm(relu(P)@W2c + bc'),
//                     block-reduce msgs -> atomicAdd msum[32].  16 agents/block.
__global__ __launch_bounds__(256) void k1(const float* __restrict__ X,
                                          const float* __restrict__ W1,
                                          const float* __restrict__ b1,
                                          float* __restrict__ ws) {
    __shared__ float4 sX4[16][16];     // X tile  [ag][k4]
    __shared__ float4 sT4[16][32];     // relu(P) [ag][c4]
    __shared__ float  sMg[16][32];     // normalized msgs
    int t = threadIdx.x;
    int a0 = blockIdx.x * 16;
    {
        int ag = t >> 4, k4 = t & 15;
        sX4[ag][k4] = ((const float4*)X)[(a0 + ag)*16 + k4];
    }
    __syncthreads();
    const int c4 = t & 31;             // col group: cols 4*c4..4*c4+3 (P) / col c4 (msgs)
    const int A0 = t >> 5, A1 = A0 + 8;
    // ---- P phase
    float4 bb = ((const float4*)b1)[c4];
    float4 acc0 = bb, acc1 = bb;
    #pragma unroll
    for (int k4 = 0; k4 < 16; ++k4) {
        float4 xA = sX4[A0][k4], xB = sX4[A1][k4];
        float4 w0 = ((const float4*)(W1 + (4*k4 + 0)*HD))[c4];
        float4 w1 = ((const float4*)(W1 + (4*k4 + 1)*HD))[c4];
        float4 w2 = ((const float4*)(W1 + (4*k4 + 2)*HD))[c4];
        float4 w3 = ((const float4*)(W1 + (4*k4 + 3)*HD))[c4];
        FMA4(acc0, xA, w0, w1, w2, w3);
        FMA4(acc1, xB, w0, w1, w2, w3);
    }
    ((float4*)(ws + P_OFF))[(a0 + A0)*32 + c4] = acc0;
    ((float4*)(ws + P_OFF))[(a0 + A1)*32 + c4] = acc1;
    float4 r0, r1;
    r0.x = fmaxf(acc0.x, 0.f); r0.y = fmaxf(acc0.y, 0.f); r0.z = fmaxf(acc0.z, 0.f); r0.w = fmaxf(acc0.w, 0.f);
    r1.x = fmaxf(acc1.x, 0.f); r1.y = fmaxf(acc1.y, 0.f); r1.z = fmaxf(acc1.z, 0.f); r1.w = fmaxf(acc1.w, 0.f);
    sT4[A0][c4] = r0;
    sT4[A1][c4] = r1;
    __syncthreads();
    // ---- M phase: msgs col c4 for agents A0, A1
    float m0 = ws[BCP_OFF + c4], m1 = m0;
    const float4* w2cT = (const float4*)(ws + W2CT_OFF);
    #pragma unroll
    for (int k4 = 0; k4 < 32; ++k4) {
        float4 ta = sT4[A0][k4], tb = sT4[A1][k4];
        float4 wc = w2cT[c4*32 + k4];
        m0 += ta.x*wc.x + ta.y*wc.y + ta.z*wc.z + ta.w*wc.w;
        m1 += tb.x*wc.x + tb.y*wc.y + tb.z*wc.z + tb.w*wc.w;
    }
    float ss0 = m0*m0, ss1 = m1*m1;
    #pragma unroll
    for (int off = 1; off < 32; off <<= 1) {
        ss0 += __shfl_xor(ss0, off);
        ss1 += __shfl_xor(ss1, off);
    }
    float rv0 = 1.f / fmaxf(sqrtf(ss0), 1e-12f);
    float rv1 = 1.f / fmaxf(sqrtf(ss1), 1e-12f);
    sMg[A0][c4] = m0 * rv0;
    sMg[A1][c4] = m1 * rv1;
    __syncthreads();
    if (t < 32) {
        float s = 0.f;
        #pragma unroll
        for (int ag = 0; ag < 16; ++ag) s += sMg[ag][t];
        atomicAdd(&ws[MSUM_OFF + t], s);
    }
}

// ---------------- K2: cvec = (msum/N)@W1b; hsum += colsum(relu(P + cvec)).  32 agents/block.
__global__ __launch_bounds__(256) void k2(const float* __restrict__ W1,
                                          float* __restrict__ ws) {
    __shared__ __align__(16) float sC[HD];
    __shared__ float4 sRed[8][32];
    int t = threadIdx.x;
    int a0 = blockIdx.x * 32;
    if (t < HD) {
        float s = 0.f;
        #pragma unroll
        for (int k = 0; k < CD; ++k) s += ws[MSUM_OFF + k] * W1[(SD + k)*HD + t];
        sC[t] = s * (1.f / (float)N_AG);
    }
    __syncthreads();
    const int c4 = t & 31, g = t >> 5;
    float4 cv = ((const float4*)sC)[c4];
    float4 acc; acc.x = acc.y = acc.z = acc.w = 0.f;
    #pragma unroll
    for (int i = 0; i < 4; ++i) {
        int ag = g + i*8;
        float4 p = ((const float4*)(ws + P_OFF))[(a0 + ag)*32 + c4];
        acc.x += fmaxf(p.x + cv.x, 0.f);
        acc.y += fmaxf(p.y + cv.y, 0.f);
        acc.z += fmaxf(p.z + cv.z, 0.f);
        acc.w += fmaxf(p.w + cv.w, 0.f);
    }
    sRed[g][c4] = acc;
    __syncthreads();
    if (t < 32) {
        float4 s = sRed[0][t];
        #pragma unroll
        for (int gg = 1; gg < 8; ++gg) {
            float4 v = sRed[gg][t];
            s.x += v.x; s.y += v.y; s.z += v.z; s.w += v.w;
        }
        atomicAdd(&ws[HSUM_OFF + 4*t + 0], s.x);
        atomicAdd(&ws[HSUM_OFF + 4*t + 1], s.y);
        atomicAdd(&ws[HSUM_OFF + 4*t + 2], s.z);
        atomicAdd(&ws[HSUM_OFF + 4*t + 3], s.w);
    }
}

// ---------------- K34: g (redundant per block) + per-agent normalize + heads.  16 agents/block.
__global__ __launch_bounds__(256) void k34(const float* __restrict__ noise,
                                           const float* __restrict__ W2, const float* __restrict__ b2,
                                           const float* __restrict__ Wg, const float* __restrict__ bg,
                                           float* __restrict__ ws, float* __restrict__ out) {
    __shared__ __align__(16) float sA[HD];
    __shared__ __align__(16) float sB[HD];
    __shared__ __align__(16) float sG[HD];
    __shared__ float4 sH4[16][32];
    int t = threadIdx.x;
    int a0 = blockIdx.x * 16;
    if (t < HD) sA[t] = ws[HSUM_OFF + t] * (1.f / (float)N_AG);
    __syncthreads();
    if (t < HD) {
        float s = b2[t];
        #pragma unroll 16
        for (int k = 0; k < HD; ++k) s += sA[k] * W2[k*HD + t];
        sB[t] = s;
    }
    __syncthreads();
    if (t < HD) {
        float s = bg[t];
        #pragma unroll 16
        for (int k = 0; k < HD; ++k) s += sB[k] * Wg[k*HD + t];
        sG[t] = fmaxf(s, 0.f);
    }
    __syncthreads();
    // ---- normalize: 16 threads per agent, 8 elems each
    const int ag = t >> 4, q = t & 15;
    const int a = a0 + ag;
    float4 n0 = ((const float4*)noise)[a*32 + q*2];
    float4 n1 = ((const float4*)noise)[a*32 + q*2 + 1];
    float4 g0 = ((const float4*)sG)[q*2];
    float4 g1 = ((const float4*)sG)[q*2 + 1];
    float4 v0, v1;
    v0.x = g0.x + 0.01f*n0.x; v0.y = g0.y + 0.01f*n0.y; v0.z = g0.z + 0.01f*n0.z; v0.w = g0.w + 0.01f*n0.w;
    v1.x = g1.x + 0.01f*n1.x; v1.y = g1.y + 0.01f*n1.y; v1.z = g1.z + 0.01f*n1.z; v1.w = g1.w + 0.01f*n1.w;
    float ss = v0.x*v0.x + v0.y*v0.y + v0.z*v0.z + v0.w*v0.w
             + v1.x*v1.x + v1.y*v1.y + v1.z*v1.z + v1.w*v1.w;
    #pragma unroll
    for (int off = 1; off < 16; off <<= 1) ss += __shfl_xor(ss, off);
    float rinv = 1.f / fmaxf(sqrtf(ss), 1e-12f);
    float4 h0, h1;
    h0.x = v0.x*rinv; h0.y = v0.y*rinv; h0.z = v0.z*rinv; h0.w = v0.w*rinv;
    h1.x = v1.x*rinv; h1.y = v1.y*rinv; h1.z = v1.z*rinv; h1.w = v1.w*rinv;
    ((float4*)out)[a*32 + q*2]     = h0;
    ((float4*)out)[a*32 + q*2 + 1] = h1;
    sH4[ag][q*2]     = h0;
    sH4[ag][q*2 + 1] = h1;
    __syncthreads();
    // ---- heads: j = q (j<12 active), 128-dot vs WallT[j]
    float acc = 0.f;
    if (q < 12) {
        acc = ws[BALL_OFF + q];
        const float4* wT = (const float4*)(ws + WALLT_OFF);
        #pragma unroll
        for (int k4 = 0; k4 < 32; ++k4) {
            float4 hh = sH4[ag][k4];
            float4 w  = wT[q*32 + k4];
            acc += hh.x*w.x + hh.y*w.y + hh.z*w.z + hh.w*w.w;
        }
    }
    // softmax sibling exchange (all lanes execute the shfls)
    int base = (t & 63) & ~15;
    float a9  = __shfl(acc, base + 9, 64);
    float a10 = __shfl(acc, base + 10, 64);
    float a11 = __shfl(acc, base + 11, 64);
    float* outA = out + N_AG*HD;
    float* outV = outA + N_AG*AD;
    float* outR = outV + N_AG;
    if (q < 8) {
        outA[a*AD + q] = tanhf(acc);
    } else if (q == 8) {
        outV[a] = acc;
    } else if (q < 12) {
        float m = fmaxf(a9, fmaxf(a10, a11));
        float d = expf(a9 - m) + expf(a10 - m) + expf(a11 - m);
        outR[a*3 + (q - 9)] = expf(acc - m) / d;
    }
}

extern "C" void kernel_launch(void* const* d_in, const int* in_sizes, int n_in,
                              void* d_out, int out_size, void* d_ws, size_t ws_size,
                              hipStream_t stream) {
    const float* states = (const float*)d_in[0];
    const float* noise  = (const float*)d_in[1];
    const float* W1 = (const float*)d_in[2];
    const float* b1 = (const float*)d_in[3];
    const float* W2 = (const float*)d_in[4];
    const float* b2 = (const float*)d_in[5];
    const float* Wc = (const float*)d_in[6];
    const float* bc = (const float*)d_in[7];
    const float* Wg = (const float*)d_in[8];
    const float* bg = (const float*)d_in[9];
    const float* Wp = (const float*)d_in[10];
    const float* bp = (const float*)d_in[11];
    const float* Wv = (const float*)d_in[12];
    const float* bv = (const float*)d_in[13];
    const float* Wr = (const float*)d_in[14];
    const float* br = (const float*)d_in[15];
    float* ws  = (float*)d_ws;
    float* out = (float*)d_out;

    hipLaunchKernelGGL(k0_pre, dim3(18),  dim3(256), 0, stream,
                       W2, b2, Wc, bc, Wp, bp, Wv, bv, Wr, br, ws);
    hipLaunchKernelGGL(k1,     dim3(512), dim3(256), 0, stream, states, W1, b1, ws);
    hipLaunchKernelGGL(k2,     dim3(256), dim3(256), 0, stream, W1, ws);
    hipLaunchKernelGGL(k34,    dim3(512), dim3(256), 0, stream,
                       noise, W2, b2, Wg, bg, ws, out);
}

// Round 8
// 144.790 us; speedup vs baseline: 1.6570x; 1.0293x over previous
//
#include <hip/hip_runtime.h>
#include <math.h>

#define N_AG 8192
#define SD 64
#define HD 128
#define CD 32
#define AD 8
#define NB1 512    // k1 blocks, 16 agents each
#define NB2 256    // k2 blocks, 32 agents each

// ws layout (floats)
#define P_OFF     0                         // N_AG*HD
#define MPART_OFF (N_AG*HD)                 // NB1*CD
#define HSUM_OFF  (MPART_OFF + NB1*CD)      // HD

#define FMA4(acc, xv, w0, w1, w2, w3)                                   \
    acc.x += xv.x*w0.x + xv.y*w1.x + xv.z*w2.x + xv.w*w3.x;             \
    acc.y += xv.x*w0.y + xv.y*w1.y + xv.z*w2.y + xv.w*w3.y;             \
    acc.z += xv.x*w0.z + xv.y*w1.z + xv.z*w2.z + xv.w*w3.z;             \
    acc.w += xv.x*w0.w + xv.y*w1.w + xv.z*w2.w + xv.w*w3.w;

// ---------------- K1: P = X@W1a + b1 (store), U = relu(P)@W2 + b2,
//                     M = U@Wc + bc, l2norm -> per-block msum partial.
__global__ __launch_bounds__(256) void k1(const float* __restrict__ X,
                                          const float* __restrict__ W1,
                                          const float* __restrict__ b1,
                                          const float* __restrict__ W2,
                                          const float* __restrict__ b2,
                                          const float* __restrict__ Wc,
                                          const float* __restrict__ bc,
                                          float* __restrict__ ws) {
    __shared__ float4 sX4[16][16];
    __shared__ float4 sT4[16][32];
    __shared__ float4 sU4[16][32];
    __shared__ float  sMg[16][CD];
    int t = threadIdx.x, b = blockIdx.x, a0 = b * 16;
    { int ag = t >> 4, k4 = t & 15; sX4[ag][k4] = ((const float4*)X)[(a0 + ag)*16 + k4]; }
    if (b == 0 && t < HD) ws[HSUM_OFF + t] = 0.f;   // zero hsum (k2 runs after all k1 blocks)
    __syncthreads();
    const int c4 = t & 31, A0 = t >> 5, A1 = A0 + 8;
    // ---- P phase
    float4 bb = ((const float4*)b1)[c4];
    float4 p0 = bb, p1 = bb;
    #pragma unroll
    for (int k4 = 0; k4 < 16; ++k4) {
        float4 xA = sX4[A0][k4], xB = sX4[A1][k4];
        float4 w0 = ((const float4*)(W1 + (4*k4 + 0)*HD))[c4];
        float4 w1 = ((const float4*)(W1 + (4*k4 + 1)*HD))[c4];
        float4 w2 = ((const float4*)(W1 + (4*k4 + 2)*HD))[c4];
        float4 w3 = ((const float4*)(W1 + (4*k4 + 3)*HD))[c4];
        FMA4(p0, xA, w0, w1, w2, w3);
        FMA4(p1, xB, w0, w1, w2, w3);
    }
    ((float4*)(ws + P_OFF))[(a0 + A0)*32 + c4] = p0;
    ((float4*)(ws + P_OFF))[(a0 + A1)*32 + c4] = p1;
    float4 r0, r1;
    r0.x = fmaxf(p0.x, 0.f); r0.y = fmaxf(p0.y, 0.f); r0.z = fmaxf(p0.z, 0.f); r0.w = fmaxf(p0.w, 0.f);
    r1.x = fmaxf(p1.x, 0.f); r1.y = fmaxf(p1.y, 0.f); r1.z = fmaxf(p1.z, 0.f); r1.w = fmaxf(p1.w, 0.f);
    sT4[A0][c4] = r0;
    sT4[A1][c4] = r1;
    __syncthreads();
    // ---- U phase: U = relu(P)@W2 + b2
    float4 b2v = ((const float4*)b2)[c4];
    float4 u0 = b2v, u1 = b2v;
    #pragma unroll
    for (int k4 = 0; k4 < 32; ++k4) {
        float4 tA = sT4[A0][k4], tB = sT4[A1][k4];
        float4 w0 = ((const float4*)(W2 + (4*k4 + 0)*HD))[c4];
        float4 w1 = ((const float4*)(W2 + (4*k4 + 1)*HD))[c4];
        float4 w2 = ((const float4*)(W2 + (4*k4 + 2)*HD))[c4];
        float4 w3 = ((const float4*)(W2 + (4*k4 + 3)*HD))[c4];
        FMA4(u0, tA, w0, w1, w2, w3);
        FMA4(u1, tB, w0, w1, w2, w3);
    }
    sU4[A0][c4] = u0;
    sU4[A1][c4] = u1;
    __syncthreads();
    // ---- M phase: col c4 for agents A0/A1
    float m0 = bc[c4], m1 = m0;
    #pragma unroll 8
    for (int k4 = 0; k4 < 32; ++k4) {
        float4 uA = sU4[A0][k4], uB = sU4[A1][k4];
        float w0 = Wc[(4*k4 + 0)*CD + c4];
        float w1 = Wc[(4*k4 + 1)*CD + c4];
        float w2 = Wc[(4*k4 + 2)*CD + c4];
        float w3 = Wc[(4*k4 + 3)*CD + c4];
        m0 += uA.x*w0 + uA.y*w1 + uA.z*w2 + uA.w*w3;
        m1 += uB.x*w0 + uB.y*w1 + uB.z*w2 + uB.w*w3;
    }
    float ss0 = m0*m0, ss1 = m1*m1;
    #pragma unroll
    for (int off = 1; off < 32; off <<= 1) {
        ss0 += __shfl_xor(ss0, off);
        ss1 += __shfl_xor(ss1, off);
    }
    sMg[A0][c4] = m0 * (1.f / fmaxf(sqrtf(ss0), 1e-12f));
    sMg[A1][c4] = m1 * (1.f / fmaxf(sqrtf(ss1), 1e-12f));
    __syncthreads();
    if (t < CD) {
        float s = 0.f;
        #pragma unroll
        for (int ag = 0; ag < 16; ++ag) s += sMg[ag][t];
        ws[MPART_OFF + b*CD + t] = s;
    }
}

// ---------------- K2: msum = reduce(mparts) (redundant/block), cvec = (msum/N)@W1b,
//                     hsum += colsum(relu(P + cvec)).  32 agents/block.
__global__ __launch_bounds__(256) void k2(const float* __restrict__ W1,
                                          float* __restrict__ ws) {
    __shared__ float sPart[8][CD];
    __shared__ float sMsum[CD];
    __shared__ __align__(16) float sC[HD];
    __shared__ float4 sRed[8][32];
    int t = threadIdx.x;
    int a0 = blockIdx.x * 32;
    {   // reduce 512 msum partials
        const int c = t & 31, chunk = t >> 5;
        float s = 0.f;
        for (int p = chunk*64; p < chunk*64 + 64; ++p)
            s += ws[MPART_OFF + p*CD + c];
        sPart[chunk][c] = s;
    }
    __syncthreads();
    if (t < CD) {
        float s = 0.f;
        #pragma unroll
        for (int j = 0; j < 8; ++j) s += sPart[j][t];
        sMsum[t] = s;
    }
    __syncthreads();
    if (t < HD) {
        float s = 0.f;
        #pragma unroll
        for (int k = 0; k < CD; ++k) s += sMsum[k] * W1[(SD + k)*HD + t];
        sC[t] = s * (1.f / (float)N_AG);
    }
    __syncthreads();
    const int c4 = t & 31, g = t >> 5;
    float4 cv = ((const float4*)sC)[c4];
    float4 acc; acc.x = acc.y = acc.z = acc.w = 0.f;
    #pragma unroll
    for (int i = 0; i < 4; ++i) {
        int ag = g + i*8;
        float4 p = ((const float4*)(ws + P_OFF))[(a0 + ag)*32 + c4];
        acc.x += fmaxf(p.x + cv.x, 0.f);
        acc.y += fmaxf(p.y + cv.y, 0.f);
        acc.z += fmaxf(p.z + cv.z, 0.f);
        acc.w += fmaxf(p.w + cv.w, 0.f);
    }
    sRed[g][c4] = acc;
    __syncthreads();
    if (t < 32) {
        float4 s = sRed[0][t];
        #pragma unroll
        for (int gg = 1; gg < 8; ++gg) {
            float4 v = sRed[gg][t];
            s.x += v.x; s.y += v.y; s.z += v.z; s.w += v.w;
        }
        atomicAdd(&ws[HSUM_OFF + 4*t + 0], s.x);
        atomicAdd(&ws[HSUM_OFF + 4*t + 1], s.y);
        atomicAdd(&ws[HSUM_OFF + 4*t + 2], s.z);
        atomicAdd(&ws[HSUM_OFF + 4*t + 3], s.w);
    }
}

// ---------------- K34: g (redundant/block) + per-agent normalize + heads.  16 agents/block.
__global__ __launch_bounds__(256) void k34(const float* __restrict__ noise,
                                           const float* __restrict__ W2, const float* __restrict__ b2,
                                           const float* __restrict__ Wg, const float* __restrict__ bg,
                                           const float* __restrict__ Wp, const float* __restrict__ bp,
                                           const float* __restrict__ Wv, const float* __restrict__ bv,
                                           const float* __restrict__ Wr, const float* __restrict__ br,
                                           const float* __restrict__ ws, float* __restrict__ out) {
    __shared__ __align__(16) float sA[HD];
    __shared__ __align__(16) float sB[HD];
    __shared__ __align__(16) float sG[HD];
    __shared__ __align__(16) float sWT[12][HD + 4];   // +4 pad: break same-bank rows
    __shared__ float sBall[12];
    __shared__ __align__(16) float4 sH4[16][33];      // 33: pad for head-phase reads
    int t = threadIdx.x;
    int a0 = blockIdx.x * 16;
    for (int idx = t; idx < 12 * HD; idx += 256) {
        int j = idx >> 7, k = idx & 127;
        sWT[j][k] = (j < 8) ? Wp[k*AD + j] : (j == 8) ? Wv[k] : Wr[k*3 + (j - 9)];
    }
    if (t < 12) sBall[t] = (t < 8) ? bp[t] : (t == 8) ? bv[0] : br[t - 9];
    if (t >= 64 && t < 64 + HD) sA[t - 64] = ws[HSUM_OFF + t - 64] * (1.f / (float)N_AG);
    __syncthreads();
    if (t < HD) {
        float s = b2[t];
        #pragma unroll 16
        for (int k = 0; k < HD; ++k) s += sA[k] * W2[k*HD + t];
        sB[t] = s;
    }
    __syncthreads();
    if (t < HD) {
        float s = bg[t];
        #pragma unroll 16
        for (int k = 0; k < HD; ++k) s += sB[k] * Wg[k*HD + t];
        sG[t] = fmaxf(s, 0.f);
    }
    __syncthreads();
    // ---- normalize: 16 threads/agent, 8 elems each
    const int ag = t >> 4, q = t & 15;
    const int a = a0 + ag;
    float4 n0 = ((const float4*)noise)[a*32 + q*2];
    float4 n1 = ((const float4*)noise)[a*32 + q*2 + 1];
    float4 g0 = ((const float4*)sG)[q*2];
    float4 g1 = ((const float4*)sG)[q*2 + 1];
    float4 v0, v1;
    v0.x = g0.x + 0.01f*n0.x; v0.y = g0.y + 0.01f*n0.y; v0.z = g0.z + 0.01f*n0.z; v0.w = g0.w + 0.01f*n0.w;
    v1.x = g1.x + 0.01f*n1.x; v1.y = g1.y + 0.01f*n1.y; v1.z = g1.z + 0.01f*n1.z; v1.w = g1.w + 0.01f*n1.w;
    float ss = v0.x*v0.x + v0.y*v0.y + v0.z*v0.z + v0.w*v0.w
             + v1.x*v1.x + v1.y*v1.y + v1.z*v1.z + v1.w*v1.w;
    #pragma unroll
    for (int off = 1; off < 16; off <<= 1) ss += __shfl_xor(ss, off);
    float rinv = 1.f / fmaxf(sqrtf(ss), 1e-12f);
    float4 h0, h1;
    h0.x = v0.x*rinv; h0.y = v0.y*rinv; h0.z = v0.z*rinv; h0.w = v0.w*rinv;
    h1.x = v1.x*rinv; h1.y = v1.y*rinv; h1.z = v1.z*rinv; h1.w = v1.w*rinv;
    ((float4*)out)[a*32 + q*2]     = h0;
    ((float4*)out)[a*32 + q*2 + 1] = h1;
    sH4[ag][q*2]     = h0;
    sH4[ag][q*2 + 1] = h1;
    __syncthreads();
    // ---- heads
    float acc = 0.f;
    if (q < 12) {
        acc = sBall[q];
        const float4* wT = (const float4*)&sWT[q][0];
        #pragma unroll
        for (int k4 = 0; k4 < 32; ++k4) {
            float4 hh = sH4[ag][k4];
            float4 w  = wT[k4];
            acc += hh.x*w.x + hh.y*w.y + hh.z*w.z + hh.w*w.w;
        }
    }
    int base = (t & 63) & ~15;
    float a9  = __shfl(acc, base + 9, 64);
    float a10 = __shfl(acc, base + 10, 64);
    float a11 = __shfl(acc, base + 11, 64);
    float* outA = out + N_AG*HD;
    float* outV = outA + N_AG*AD;
    float* outR = outV + N_AG;
    if (q < 8) {
        outA[a*AD + q] = tanhf(acc);
    } else if (q == 8) {
        outV[a] = acc;
    } else if (q < 12) {
        float m = fmaxf(a9, fmaxf(a10, a11));
        float d = expf(a9 - m) + expf(a10 - m) + expf(a11 - m);
        outR[a*3 + (q - 9)] = expf(acc - m) / d;
    }
}

extern "C" void kernel_launch(void* const* d_in, const int* in_sizes, int n_in,
                              void* d_out, int out_size, void* d_ws, size_t ws_size,
                              hipStream_t stream) {
    const float* states = (const float*)d_in[0];
    const float* noise  = (const float*)d_in[1];
    const float* W1 = (const float*)d_in[2];
    const float* b1 = (const float*)d_in[3];
    const float* W2 = (const float*)d_in[4];
    const float* b2 = (const float*)d_in[5];
    const float* Wc = (const float*)d_in[6];
    const float* bc = (const float*)d_in[7];
    const float* Wg = (const float*)d_in[8];
    const float* bg = (const float*)d_in[9];
    const float* Wp = (const float*)d_in[10];
    const float* bp = (const float*)d_in[11];
    const float* Wv = (const float*)d_in[12];
    const float* bv = (const float*)d_in[13];
    const float* Wr = (const float*)d_in[14];
    const float* br = (const float*)d_in[15];
    float* ws  = (float*)d_ws;
    float* out = (float*)d_out;

    hipLaunchKernelGGL(k1,  dim3(NB1), dim3(256), 0, stream,
                       states, W1, b1, W2, b2, Wc, bc, ws);
    hipLaunchKernelGGL(k2,  dim3(NB2), dim3(256), 0, stream, W1, ws);
    hipLaunchKernelGGL(k34, dim3(NB1), dim3(256), 0, stream,
                       noise, W2, b2, Wg, bg, Wp, bp, Wv, bv, Wr, br, ws, out);
}